// Round 7
// baseline (477.951 us; speedup 1.0000x reference)
//
#include <hip/hip_runtime.h>

#define GAMMA 0.1f
#define MIN_R 0.1f
#define THR 256
#define THR_P 128

typedef unsigned int u32;

// ---------------- LJ force accumulate ----------------------------------------
__device__ __forceinline__ void lj_accum(float4 xd, float4 xs,
                                         float& ax, float& ay, float& az)
{
    float dx = xd.x - xs.x, dy = xd.y - xs.y, dz = xd.z - xs.z;
    float r2 = dx * dx + dy * dy + dz * dz;
    float rr = sqrtf(r2);
    float inv_norm = 1.0f / fmaxf(rr, 1e-12f);
    float rc = fmaxf(rr, MIN_R);
    float s1 = 1.0f / rc;                 // RC = 1
    float s2 = s1 * s1;
    float s6 = s2 * s2 * s2;
    float F = 4.0f * s6 * (12.0f * s6 - 6.0f) * s1;
    float sc = F * inv_norm;
    ax += sc * dx; ay += sc * dy; az += sc * dz;
}

// ---------------- k0: pack x into float4, zero per-node counters -------------
__global__ void prep_kernel(const float* __restrict__ x,
                            float4* __restrict__ xp,
                            u32* __restrict__ cnt, int n_nodes)
{
    int i = blockIdx.x * blockDim.x + threadIdx.x;
    if (i <= n_nodes) cnt[i] = 0u;
    if (i < n_nodes)
        xp[i] = make_float4(x[3 * i + 0], x[3 * i + 1], x[3 * i + 2], 0.0f);
}

// ---------------- k1: per-node degree histogram ------------------------------
__global__ void count_kernel(const int* __restrict__ dst,
                             u32* __restrict__ cnt, int n_edges)
{
    int i4 = (blockIdx.x * blockDim.x + threadIdx.x) * 4;
    if (i4 + 3 < n_edges) {
        int4 d4 = *(const int4*)(dst + i4);
        atomicAdd(&cnt[d4.x], 1u);
        atomicAdd(&cnt[d4.y], 1u);
        atomicAdd(&cnt[d4.z], 1u);
        atomicAdd(&cnt[d4.w], 1u);
    } else {
        for (int e = i4; e < n_edges; ++e)
            atomicAdd(&cnt[dst[e]], 1u);
    }
}

// ---------------- k2: per-chunk exclusive scan (1024-wide) -------------------
__global__ __launch_bounds__(1024) void scan1_kernel(
    const u32* __restrict__ cnt, u32* __restrict__ starts,
    u32* __restrict__ partials, int n)
{
    __shared__ u32 s[1024];
    const int b = blockIdx.x, t = threadIdx.x;
    const int gid = b * 1024 + t;
    u32 orig = (gid < n) ? cnt[gid] : 0u;
    s[t] = orig;
    __syncthreads();
    for (int d = 1; d < 1024; d <<= 1) {
        u32 v = (t >= d) ? s[t - d] : 0u;
        __syncthreads();
        s[t] += v;
        __syncthreads();
    }
    if (gid < n) starts[gid] = s[t] - orig;   // chunk-exclusive
    if (t == 1023) partials[b] = s[t];        // chunk total
}

// ---------------- k3: scan chunk totals (single block) -----------------------
__global__ __launch_bounds__(1024) void scan2_kernel(
    u32* __restrict__ partials, u32* __restrict__ starts, int nb, int n)
{
    __shared__ u32 s[1024];
    const int t = threadIdx.x;
    u32 orig = (t < nb) ? partials[t] : 0u;
    s[t] = orig;
    __syncthreads();
    for (int d = 1; d < 1024; d <<= 1) {
        u32 v = (t >= d) ? s[t - d] : 0u;
        __syncthreads();
        s[t] += v;
        __syncthreads();
    }
    if (t < nb) partials[t] = s[t] - orig;    // exclusive chunk offsets
    if (t == 1023) starts[n] = s[t];          // grand total
}

// ---------------- k4: add chunk offsets; init cursors ------------------------
__global__ __launch_bounds__(1024) void scan3_kernel(
    u32* __restrict__ starts, u32* __restrict__ cursor,
    const u32* __restrict__ partials, int n)
{
    const int b = blockIdx.x, t = threadIdx.x;
    const int gid = b * 1024 + t;
    if (gid < n) {
        u32 v = starts[gid] + partials[b];
        starts[gid] = v;
        cursor[gid] = v;
    }
}

// ---------------- k5: scatter src ids into per-node segments -----------------
__global__ void scatter_kernel(const int* __restrict__ src,
                               const int* __restrict__ dst,
                               u32* __restrict__ cursor,
                               u32* __restrict__ pk, int n_edges)
{
    int i4 = (blockIdx.x * blockDim.x + threadIdx.x) * 4;
    if (i4 + 3 < n_edges) {
        int4 d4 = *(const int4*)(dst + i4);
        int4 s4 = *(const int4*)(src + i4);
        u32 p;
        p = atomicAdd(&cursor[d4.x], 1u); pk[p] = (u32)s4.x;
        p = atomicAdd(&cursor[d4.y], 1u); pk[p] = (u32)s4.y;
        p = atomicAdd(&cursor[d4.z], 1u); pk[p] = (u32)s4.z;
        p = atomicAdd(&cursor[d4.w], 1u); pk[p] = (u32)s4.w;
    } else {
        for (int e = i4; e < n_edges; ++e) {
            u32 p = atomicAdd(&cursor[dst[e]], 1u);
            pk[p] = (u32)src[e];
        }
    }
}

// ---------------- k6: per-node register-accumulated gather + fused output ----
__global__ __launch_bounds__(THR_P) void process_kernel(
    const float4* __restrict__ xp, const u32* __restrict__ pk,
    const u32* __restrict__ starts, const float* __restrict__ v,
    float* __restrict__ out, int n_nodes)
{
    const int d = blockIdx.x * THR_P + threadIdx.x;
    if (d >= n_nodes) return;
    const float4 xd = xp[d];
    const int e0 = (int)starts[d];
    const int e1 = (int)starts[d + 1];
    float ax = 0.0f, ay = 0.0f, az = 0.0f;

    int e = e0;
    const int e4 = e0 + ((e1 - e0) & ~3);
    for (; e < e4; e += 4) {
        u32 sA = pk[e + 0], sB = pk[e + 1], sC = pk[e + 2], sD = pk[e + 3];
        float4 a = xp[sA];
        float4 b = xp[sB];
        float4 c = xp[sC];
        float4 f = xp[sD];
        lj_accum(xd, a, ax, ay, az);
        lj_accum(xd, b, ax, ay, az);
        lj_accum(xd, c, ax, ay, az);
        lj_accum(xd, f, ax, ay, az);
    }
    for (; e < e1; ++e) {
        u32 s = pk[e];
        float4 a = xp[s];
        lj_accum(xd, a, ax, ay, az);
    }

    out[3 * d + 0] = ax - GAMMA * v[3 * d + 0];
    out[3 * d + 1] = ay - GAMMA * v[3 * d + 1];
    out[3 * d + 2] = az - GAMMA * v[3 * d + 2];
}

// ---------------- fallback path (ws too small / too many nodes) --------------
__global__ void init_out_kernel(const float* __restrict__ v,
                                float* __restrict__ out, int n) {
    int i = blockIdx.x * blockDim.x + threadIdx.x;
    if (i < n) out[i] = -GAMMA * v[i];
}

__global__ void edge_atomic_kernel(const float* __restrict__ x,
                                   const int* __restrict__ src,
                                   const int* __restrict__ dst,
                                   float* __restrict__ out, int n_edges) {
    int t = blockIdx.x * blockDim.x + threadIdx.x;
    if (t < n_edges) {
        int s = src[t], d = dst[t];
        float dx = x[3 * d + 0] - x[3 * s + 0];
        float dy = x[3 * d + 1] - x[3 * s + 1];
        float dz = x[3 * d + 2] - x[3 * s + 2];
        float r2 = dx * dx + dy * dy + dz * dz;
        float rr = sqrtf(r2);
        float inv_norm = 1.0f / fmaxf(rr, 1e-12f);
        float rc = fmaxf(rr, MIN_R);
        float s1 = 1.0f / rc;
        float s2 = s1 * s1;
        float s6 = s2 * s2 * s2;
        float F = 4.0f * s6 * (12.0f * s6 - 6.0f) * s1;
        float sc = F * inv_norm;
        unsafeAtomicAdd(&out[3 * d + 0], sc * dx);
        unsafeAtomicAdd(&out[3 * d + 1], sc * dy);
        unsafeAtomicAdd(&out[3 * d + 2], sc * dz);
    }
}

extern "C" void kernel_launch(void* const* d_in, const int* in_sizes, int n_in,
                              void* d_out, int out_size, void* d_ws, size_t ws_size,
                              hipStream_t stream) {
    const float* x   = (const float*)d_in[0];
    const float* v   = (const float*)d_in[1];
    const int*   src = (const int*)d_in[2];
    const int*   dst = (const int*)d_in[3];
    float* out = (float*)d_out;

    const int n_out = out_size;
    const int n_nodes = out_size / 3;
    const int n_edges = in_sizes[2];

    // ws layout (bytes)
    const size_t xp_bytes  = (((size_t)n_nodes * 16) + 63) & ~(size_t)63;
    const size_t tbl_bytes = (((size_t)(n_nodes + 1) * 4) + 63) & ~(size_t)63;
    const size_t cnt_off    = xp_bytes;
    const size_t starts_off = cnt_off + tbl_bytes;
    const size_t cursor_off = starts_off + tbl_bytes;
    const size_t part_off   = cursor_off + tbl_bytes;
    const size_t pk_off     = part_off + 4096;
    const size_t need       = pk_off + (size_t)n_edges * 4;

    const int B1 = (n_nodes + 1023) / 1024;   // scan chunks
    const bool fast = (B1 >= 1) && (B1 <= 1024) && (need <= ws_size);

    const int blk = THR;
    if (fast) {
        float4* xp      = (float4*)d_ws;
        u32*    cnt     = (u32*)((char*)d_ws + cnt_off);
        u32*    starts  = (u32*)((char*)d_ws + starts_off);
        u32*    cursor  = (u32*)((char*)d_ws + cursor_off);
        u32*    partials= (u32*)((char*)d_ws + part_off);
        u32*    pk      = (u32*)((char*)d_ws + pk_off);

        const int e4grid = ((n_edges + 3) / 4 + blk - 1) / blk;

        prep_kernel<<<(n_nodes + 1 + blk - 1) / blk, blk, 0, stream>>>(
            x, xp, cnt, n_nodes);
        count_kernel<<<e4grid, blk, 0, stream>>>(dst, cnt, n_edges);
        scan1_kernel<<<B1, 1024, 0, stream>>>(cnt, starts, partials, n_nodes);
        scan2_kernel<<<1, 1024, 0, stream>>>(partials, starts, B1, n_nodes);
        scan3_kernel<<<B1, 1024, 0, stream>>>(starts, cursor, partials, n_nodes);
        scatter_kernel<<<e4grid, blk, 0, stream>>>(src, dst, cursor, pk, n_edges);
        process_kernel<<<(n_nodes + THR_P - 1) / THR_P, THR_P, 0, stream>>>(
            xp, pk, starts, v, out, n_nodes);
    } else {
        init_out_kernel<<<(n_out + blk - 1) / blk, blk, 0, stream>>>(v, out, n_out);
        edge_atomic_kernel<<<(n_edges + blk - 1) / blk, blk, 0, stream>>>(
            x, src, dst, out, n_edges);
    }
}